// Round 10
// baseline (546.387 us; speedup 1.0000x reference)
//
#include <hip/hip_runtime.h>
#include <stdint.h>

// HeadwiseLowRankModule: out = blockdiag-GEMM(GEMM(hidden, VT^T), U^T), f32 I/O.
// ROUND 10: r9 proven baseline (545us) + T1 XCD-aware block swizzle on both
// GEMMs (bijective flat-id remap; each XCD owns a contiguous M-stripe so
// A/latent row-panels become XCD-L2-local). Kernel bodies unchanged from r9.

typedef short  bf16x8  __attribute__((ext_vector_type(8)));
typedef float  f32x4   __attribute__((ext_vector_type(4)));
typedef ushort ushort8 __attribute__((ext_vector_type(8)));
typedef float  flt4    __attribute__((ext_vector_type(4)));

__device__ __forceinline__ void gload_lds16(const ushort* g, ushort* l) {
    __builtin_amdgcn_global_load_lds(
        (const __attribute__((address_space(1))) uint32_t*)g,
        (__attribute__((address_space(3))) uint32_t*)l, 16, 0, 0);
}

__device__ __forceinline__ ushort f2bf(float f) {
    union { float f; uint32_t u; } c; c.f = f;
    uint32_t u = c.u;
    uint32_t r = (u + 0x7FFFu + ((u >> 16) & 1u)) >> 16;  // RNE
    return (ushort)r;
}

// ---- fused f32 -> bf16 conversion for all three inputs (one launch) ----
__device__ __forceinline__ void conv_seg(const float* __restrict__ in,
                                         ushort* __restrict__ out,
                                         long n8, int bid, int nblk) {
    const long stride = (long)nblk * 256;
    for (long i = (long)bid * 256 + threadIdx.x; i < n8; i += stride) {
        flt4 a = ((const flt4*)in)[2 * i];
        flt4 b = ((const flt4*)in)[2 * i + 1];
        ushort8 o;
        o[0] = f2bf(a[0]); o[1] = f2bf(a[1]); o[2] = f2bf(a[2]); o[3] = f2bf(a[3]);
        o[4] = f2bf(b[0]); o[5] = f2bf(b[1]); o[6] = f2bf(b[2]); o[7] = f2bf(b[3]);
        ((ushort8*)out)[i] = o;
    }
}

__global__ __launch_bounds__(256) void convert_all_kernel(
    const float* __restrict__ hid_f, ushort* __restrict__ hid_b, long nHid8,
    const float* __restrict__ vt_f,  ushort* __restrict__ vt_b,  long nVT8,
    const float* __restrict__ u_f,   ushort* __restrict__ u_b,   long nU8)
{
    const int b = blockIdx.x;
    if (b < 1792)      conv_seg(hid_f, hid_b, nHid8, b,        1792);
    else if (b < 2016) conv_seg(vt_f,  vt_b,  nVT8,  b - 1792, 224);
    else               conv_seg(u_f,   u_b,   nU8,   b - 2016, 32);
}

// ---- store helpers (bf16 or f32 output) ----
__device__ __forceinline__ void store_out(ushort* p, float v) { *p = f2bf(v); }
__device__ __forceinline__ void store_out(float*  p, float v) { *p = v; }

// C[M x ldc] = A[. x lda] * B[. x ldb]^T  (A,B bf16 row-major, K contiguous)
// blockIdx.z applies flat element offsets (block-diagonal GEMM2).
// PROVEN r2/r9 kernel body. NEW: flat blockIdx.x -> (bx,by) via XCD swizzle:
//   xcd = bid&7; r = bid>>3; by = xcd*16 + (r>>bxShift); bx = r&(2^bxShift-1)
// Requires gridDim.x == 8 * 16 * 2^bxShift (M fixed at 128 tiles).
template <typename TOUT>
__global__ __launch_bounds__(256) void gemm_bt_kernel(
    const ushort* __restrict__ A,
    const ushort* __restrict__ B,
    TOUT* __restrict__ C,
    int lda, int ldb, int ldc, int K, int bxShift,
    long aOffZ, long bOffZ, long cOffZ)
{
    A += (size_t)blockIdx.z * aOffZ;
    B += (size_t)blockIdx.z * bOffZ;
    C += (size_t)blockIdx.z * cOffZ;

    __shared__ ushort As[128 * 64];   // 16 KiB, linear (global_load_lds dest)
    __shared__ ushort Bs[128 * 64];   // 16 KiB

    const int tid  = threadIdx.x;
    const int lane = tid & 63;
    const int wave = tid >> 6;

    // XCD-aware swizzle: XCD k owns M-stripe [k*16*128, (k+1)*16*128)
    const int bid = blockIdx.x;
    const int xcd = bid & 7;
    const int rr  = bid >> 3;
    const int by  = xcd * 16 + (rr >> bxShift);
    const int bx  = rr & ((1 << bxShift) - 1);

    const int row0 = by * 128;
    const int col0 = bx * 128;

    const int wr = wave >> 1;
    const int wc = wave & 1;

    const int l15    = lane & 15;
    const int lq     = lane >> 4;    // 0..3
    const int lrow   = lane >> 3;    // 0..7 (staging row in 8-row segment)
    const int lchunk = lane & 7;     // 0..7 (16B chunk within row)

    f32x4 acc[4][4] = {};

    const ushort* aPtr = A + (size_t)(row0 + wave * 32 + lrow) * lda + lchunk * 8;
    const ushort* bPtr = B + (size_t)(col0 + wave * 32 + lrow) * ldb + lchunk * 8;

    const int nkt = K / 64;
    for (int kt = 0; kt < nkt; ++kt) {
        const int kOff = kt * 64;
        __syncthreads();
        #pragma unroll
        for (int i = 0; i < 4; ++i) {
            gload_lds16(aPtr + (size_t)i * 8 * lda + kOff, As + (wave * 4 + i) * 512);
            gload_lds16(bPtr + (size_t)i * 8 * ldb + kOff, Bs + (wave * 4 + i) * 512);
        }
        __syncthreads();

        #pragma unroll
        for (int kk = 0; kk < 2; ++kk) {
            bf16x8 af[4], bfr[4];
            #pragma unroll
            for (int m = 0; m < 4; ++m)
                af[m] = *(const bf16x8*)&As[(wr * 64 + m * 16 + l15) * 64 + kk * 32 + lq * 8];
            #pragma unroll
            for (int n = 0; n < 4; ++n)
                bfr[n] = *(const bf16x8*)&Bs[(wc * 64 + n * 16 + l15) * 64 + kk * 32 + lq * 8];
            #pragma unroll
            for (int m = 0; m < 4; ++m)
                #pragma unroll
                for (int n = 0; n < 4; ++n)
                    acc[m][n] = __builtin_amdgcn_mfma_f32_16x16x32_bf16(
                        af[m], bfr[n], acc[m][n], 0, 0, 0);
        }
    }

    // C/D layout: col = lane&15, row = (lane>>4)*4 + reg  [m89/m91 verified]
    #pragma unroll
    for (int m = 0; m < 4; ++m) {
        #pragma unroll
        for (int r = 0; r < 4; ++r) {
            const size_t row = (size_t)(row0 + wr * 64 + m * 16 + lq * 4 + r);
            TOUT* cRow = C + row * ldc + col0 + wc * 64 + l15;
            #pragma unroll
            for (int n = 0; n < 4; ++n)
                store_out(cRow + n * 16, acc[m][n][r]);
        }
    }
}

extern "C" void kernel_launch(void* const* d_in, const int* in_sizes, int n_in,
                              void* d_out, int out_size, void* d_ws, size_t ws_size,
                              hipStream_t stream) {
    const float* hidden_f = (const float*)d_in[0];  // 16384 x 4096 f32
    const float* VT_f     = (const float*)d_in[1];  // 2048 x 4096 f32 (N,K)
    const float* U_f      = (const float*)d_in[2];  // 8 x 512 x 256 f32
    float* out = (float*)d_out;                     // 16384 x 4096 f32

    const long nHid = 16384L * 4096L;
    const long nVT  = 2048L * 4096L;
    const long nU   = 8L * 512L * 256L;
    const long nLat = 16384L * 2048L;

    ushort *hid_b, *vt_b, *u_b, *lat_b;
    const size_t needA = (size_t)(nHid + nVT + nU + nLat) * 2;
    if (ws_size >= needA) {
        ushort* w = (ushort*)d_ws;
        hid_b = w;  vt_b = hid_b + nHid;  u_b = vt_b + nVT;  lat_b = u_b + nU;
    } else {
        ushort* w = (ushort*)d_ws;
        lat_b = w;  u_b = lat_b + nLat;
        ushort* o = (ushort*)d_out;       // staged in d_out; fully overwritten by GEMM2
        hid_b = o;  vt_b = hid_b + nHid;
    }

    // fused input conversion (one launch)
    convert_all_kernel<<<dim3(2048), dim3(256), 0, stream>>>(
        hidden_f, hid_b, nHid / 8,
        VT_f,     vt_b,  nVT / 8,
        U_f,      u_b,   nU / 8);

    // GEMM1: latent[16384 x 2048] = hid * VT^T
    // flat grid 2048 = 8 xcd * 16 stripe-rows * 16 col tiles (bxShift=4)
    gemm_bt_kernel<ushort><<<dim3(2048, 1, 1), dim3(256), 0, stream>>>(
        hid_b, vt_b, lat_b, 4096, 4096, 2048, 4096, 4,
        0L, 0L, 0L);

    // GEMM2 (block-diag): out[:, g*512:+512] = latent[:, g*256:+256] * U[g]^T
    // per-z flat grid 512 = 8 xcd * 16 stripe-rows * 4 col tiles (bxShift=2);
    // z*512 % 8 == 0 keeps the xcd alignment per group.
    gemm_bt_kernel<float><<<dim3(512, 1, 8), dim3(256), 0, stream>>>(
        lat_b, u_b, out, 2048, 256, 4096, 256, 2,
        256L, 512L * 256L, 512L);
}